// Round 3
// baseline (30365.012 us; speedup 1.0000x reference)
//
#include <hip/hip_runtime.h>

// Problem constants (from reference)
#define BB    2048
#define TT    100
#define CC    8
#define HD    64
#define HHD   128
#define OO    10
#define MROWS 8      // batch rows per block; grid = 256 blocks, 1 block/CU
#define NTHR  512    // 8 waves; __launch_bounds__(512,2) -> 256-VGPR budget

__device__ __forceinline__ float fast_tanh(float x) {
  float e = __expf(2.0f * x);
  return 1.0f - 2.0f / (e + 1.0f);
}

__global__ void zero_out_k(float* o) {
  if (threadIdx.x < 2) o[threadIdx.x] = 0.0f;
}

// hidden layer k-slice: relu(part_in) x wh(2 cols, 16 k) -> ds_add into part_out
// cols owned: (l, l+64)  [conflict-free atomics: 64 lanes -> 2 lanes/bank]
__device__ __forceinline__ void hidden_adds(const float2 (&wh)[16],
                                            const float (*pin)[HHD],
                                            float (*pout)[HHD],
                                            int l, int kb) {
#pragma unroll 2
  for (int r = 0; r < MROWS; ++r) {
    const float4 h0 = *(const float4*)&pin[r][kb+0];    // wave-uniform -> broadcast
    const float4 h1 = *(const float4*)&pin[r][kb+4];
    const float4 h2 = *(const float4*)&pin[r][kb+8];
    const float4 h3 = *(const float4*)&pin[r][kb+12];
    const float hk[16] = {
      fmaxf(h0.x,0.f), fmaxf(h0.y,0.f), fmaxf(h0.z,0.f), fmaxf(h0.w,0.f),
      fmaxf(h1.x,0.f), fmaxf(h1.y,0.f), fmaxf(h1.z,0.f), fmaxf(h1.w,0.f),
      fmaxf(h2.x,0.f), fmaxf(h2.y,0.f), fmaxf(h2.z,0.f), fmaxf(h2.w,0.f),
      fmaxf(h3.x,0.f), fmaxf(h3.y,0.f), fmaxf(h3.z,0.f), fmaxf(h3.w,0.f) };
    float a0 = 0.f, a1 = 0.f;
#pragma unroll
    for (int k = 0; k < 16; ++k) {
      a0 = fmaf(hk[k], wh[k].x, a0);
      a1 = fmaf(hk[k], wh[k].y, a1);
    }
    atomicAdd(&pout[r][l],      a0);
    atomicAdd(&pout[r][l + 64], a1);
  }
}

__global__ void __launch_bounds__(NTHR, 2)
cde_main(const float* __restrict__ coeffs, const int* __restrict__ yy,
         const float* __restrict__ times,
         const float* __restrict__ W_init, const float* __restrict__ b_init,
         const float* __restrict__ W_in,  const float* __restrict__ b_in,
         const float* __restrict__ W_h,   const float* __restrict__ b_h,
         const float* __restrict__ W_out, const float* __restrict__ b_out,
         const float* __restrict__ W_read,const float* __restrict__ b_read,
         float* __restrict__ out)
{
  __shared__ float sZs[MROWS][HD];        // 2KB   stage-input z
  __shared__ float pA [MROWS][HHD];       // 4KB   bias-primed partials, layer A
  __shared__ float p1 [MROWS][HHD];       // 4KB   hidden1
  __shared__ float p2 [MROWS][HHD];       // 4KB   hidden2
  __shared__ float pB [MROWS][576];       // 18KB  big layer, addr = col + (col>>3)
  __shared__ float sDx[MROWS][CC];
  __shared__ float sLog[MROWS][OO];

  const int t    = threadIdx.x;
  const int wv   = t >> 6;        // wave id 0..7  (k-slice owner; epilogue row)
  const int l    = t & 63;        // lane          (col owner; epilogue h)
  const int row0 = blockIdx.x * MROWS;

  // ---- register-stationary weight slices (208 VGPRs) ----
  float2 winR[8];                 // {W_in[k][l], W_in[k][l+64]}, k in [8wv, 8wv+8)
#pragma unroll
  for (int j = 0; j < 8; ++j) {
    const float* wr = W_in + (8*wv + j)*HHD;
    winR[j] = make_float2(wr[l], wr[l + 64]);
  }
  float2 wh1[16], wh2[16];        // k in [16wv, 16wv+16)
#pragma unroll
  for (int j = 0; j < 16; ++j) {
    const float* w1 = W_h + (16*wv + j)*HHD;
    const float* w2 = W_h + HHD*HHD + (16*wv + j)*HHD;
    wh1[j] = make_float2(w1[l], w1[l + 64]);
    wh2[j] = make_float2(w2[l], w2[l + 64]);
  }
  float wout[128];                // [k 0..15][j 0..7] = W_out[16wv+k][l+64j]
#pragma unroll
  for (int k = 0; k < 16; ++k)
#pragma unroll
    for (int j = 0; j < 8; ++j)
      wout[k*8 + j] = W_out[(16*wv + k)*(HD*CC) + (l + 64*j)];

  const float2 binv  = make_float2(b_in[l],        b_in[l + 64]);
  const float2 bh1v  = make_float2(b_h[l],         b_h[l + 64]);
  const float2 bh2v  = make_float2(b_h[HHD + l],   b_h[HHD + l + 64]);
  const float  boutv = b_out[t];

  // ---- z0 ; thread owns (row wv, h=l) ----
  float z0, kacc = 0.f;
  {
    const float* cf = coeffs + (size_t)(row0 + wv) * (TT*CC);
    float a = b_init[l];
#pragma unroll
    for (int c = 0; c < CC; ++c) a = fmaf(cf[c], W_init[c*HD + l], a);
    z0 = a;
    sZs[wv][l] = a;
  }

  // ---- prime partial buffers with bias ----
  pA[wv][l] = binv.x;  pA[wv][l + 64] = binv.y;
  p1[wv][l] = bh1v.x;  p1[wv][l + 64] = bh1v.y;
  p2[wv][l] = bh2v.x;  p2[wv][l + 64] = bh2v.y;
#pragma unroll
  for (int r = 0; r < MROWS; ++r) pB[r][t + (t >> 3)] = boutv;
  __syncthreads();

#pragma unroll 1
  for (int step = 0; step < TT-1; ++step) {
    const float dti = times[step+1] - times[step];
    if (t < 64) {   // written in P1 region; last reader (prev P5) is behind a barrier
      const int r = t >> 3, c = t & 7;
      const float* cf = coeffs + (size_t)(row0 + r)*(TT*CC) + step*CC + c;
      sDx[r][c] = (cf[CC] - cf[0]) / dti;
    }

#pragma unroll 1
    for (int s = 0; s < 4; ++s) {
      // ---- P1: layer A adds (reads sZs raw) + rebias pB ----
      {
        const int kb = 8*wv;
#pragma unroll 2
        for (int r = 0; r < MROWS; ++r) {
          const float4 za = *(const float4*)&sZs[r][kb];
          const float4 zb = *(const float4*)&sZs[r][kb+4];
          const float zk[8] = {za.x, za.y, za.z, za.w, zb.x, zb.y, zb.z, zb.w};
          float a0 = 0.f, a1 = 0.f;
#pragma unroll
          for (int k = 0; k < 8; ++k) {
            a0 = fmaf(zk[k], winR[k].x, a0);
            a1 = fmaf(zk[k], winR[k].y, a1);
          }
          atomicAdd(&pA[r][l],      a0);
          atomicAdd(&pA[r][l + 64], a1);
        }
#pragma unroll
        for (int r = 0; r < MROWS; ++r) pB[r][t + (t >> 3)] = boutv;
      }
      __syncthreads();
      // ---- P2: hidden1 adds (reads pA, relu inline) ----
      hidden_adds(wh1, pA, p1, l, 16*wv);
      __syncthreads();
      // ---- P3: hidden2 adds (reads p1, relu inline) + rebias pA ----
      hidden_adds(wh2, p1, p2, l, 16*wv);
      pA[wv][l] = binv.x;  pA[wv][l + 64] = binv.y;
      __syncthreads();
      // ---- P4: big layer adds (reads p2, relu inline) + rebias p1 ----
      {
        const int kb = 16*wv;
#pragma unroll 2
        for (int r = 0; r < MROWS; ++r) {
          const float4 h0 = *(const float4*)&p2[r][kb+0];
          const float4 h1 = *(const float4*)&p2[r][kb+4];
          const float4 h2 = *(const float4*)&p2[r][kb+8];
          const float4 h3 = *(const float4*)&p2[r][kb+12];
          const float hk[16] = {
            fmaxf(h0.x,0.f), fmaxf(h0.y,0.f), fmaxf(h0.z,0.f), fmaxf(h0.w,0.f),
            fmaxf(h1.x,0.f), fmaxf(h1.y,0.f), fmaxf(h1.z,0.f), fmaxf(h1.w,0.f),
            fmaxf(h2.x,0.f), fmaxf(h2.y,0.f), fmaxf(h2.z,0.f), fmaxf(h2.w,0.f),
            fmaxf(h3.x,0.f), fmaxf(h3.y,0.f), fmaxf(h3.z,0.f), fmaxf(h3.w,0.f) };
          float acc[8] = {0.f,0.f,0.f,0.f,0.f,0.f,0.f,0.f};
#pragma unroll
          for (int k = 0; k < 16; ++k) {
            const float hv = hk[k];
#pragma unroll
            for (int j = 0; j < 8; ++j)
              acc[j] = fmaf(hv, wout[k*8 + j], acc[j]);
          }
#pragma unroll
          for (int j = 0; j < 8; ++j) {
            const int col = l + 64*j;
            atomicAdd(&pB[r][col + (col >> 3)], acc[j]);
          }
        }
        p1[wv][l] = bh1v.x;  p1[wv][l + 64] = bh1v.y;
      }
      __syncthreads();
      // ---- P5: epilogue (tanh, einsum dX, RK) + rebias p2 ----
      {
        const float* pr = &pB[wv][9*l];     // cols 8l..8l+7 of row wv
        const float u0 = pr[0], u1 = pr[1], u2 = pr[2], u3 = pr[3];
        const float u4 = pr[4], u5 = pr[5], u6 = pr[6], u7 = pr[7];
        const float4 d0 = *(const float4*)&sDx[wv][0];   // broadcast
        const float4 d1 = *(const float4*)&sDx[wv][4];
        float g = fast_tanh(u0)*d0.x + fast_tanh(u1)*d0.y
                + fast_tanh(u2)*d0.z + fast_tanh(u3)*d0.w
                + fast_tanh(u4)*d1.x + fast_tanh(u5)*d1.y
                + fast_tanh(u6)*d1.z + fast_tanh(u7)*d1.w;
        if (s == 0)      kacc = g;
        else if (s == 3) kacc += g;
        else             kacc += 2.0f * g;
        float zs;
        if (s == 3) {
          z0 = z0 + dti * (1.0f/6.0f) * kacc;
          zs = z0;
        } else {
          zs = z0 + ((s == 2) ? dti : 0.5f * dti) * g;
        }
        sZs[wv][l] = zs;
        p2[wv][l] = bh2v.x;  p2[wv][l + 64] = bh2v.y;
      }
      __syncthreads();
    } // stages
  }   // steps

  // ---- readout: logits = zT @ W_read + b_read ; loss + accuracy ----
  if (t < MROWS * OO) {
    const int r = t / OO, o = t % OO;
    float a = b_read[o];
#pragma unroll 8
    for (int k = 0; k < HD; ++k) a = fmaf(sZs[r][k], W_read[k*OO + o], a);
    sLog[r][o] = a;
  }
  __syncthreads();
  if (t < 64) {
    float lv = 0.f, cv = 0.f;
    if (t < MROWS) {
      const int r = t;
      float mx = sLog[r][0]; int am = 0;
#pragma unroll
      for (int o = 1; o < OO; ++o) { const float v = sLog[r][o]; if (v > mx) { mx = v; am = o; } }
      float se = 0.f;
#pragma unroll
      for (int o = 0; o < OO; ++o) se += expf(sLog[r][o] - mx);
      const float lse = mx + logf(se);
      const int yr = yy[row0 + r];
      lv = (lse - sLog[r][yr]) * (1.0f / (float)BB);
      cv = (am == yr) ? 1.0f : 0.0f;
    }
    lv += __shfl_xor(lv, 1); lv += __shfl_xor(lv, 2); lv += __shfl_xor(lv, 4);
    cv += __shfl_xor(cv, 1); cv += __shfl_xor(cv, 2); cv += __shfl_xor(cv, 4);
    if (t == 0) { atomicAdd(&out[0], lv); atomicAdd(&out[1], cv); }
  }
}

extern "C" void kernel_launch(void* const* d_in, const int* in_sizes, int n_in,
                              void* d_out, int out_size, void* d_ws, size_t ws_size,
                              hipStream_t stream) {
  const float* coeffs = (const float*)d_in[0];
  const int*   y      = (const int*)  d_in[1];
  const float* times  = (const float*)d_in[2];
  const float* W_init = (const float*)d_in[3];
  const float* b_init = (const float*)d_in[4];
  const float* W_in   = (const float*)d_in[5];
  const float* b_in   = (const float*)d_in[6];
  const float* W_h    = (const float*)d_in[7];
  const float* b_h    = (const float*)d_in[8];
  const float* W_out  = (const float*)d_in[9];
  const float* b_out  = (const float*)d_in[10];
  const float* W_read = (const float*)d_in[11];
  const float* b_read = (const float*)d_in[12];
  float* out = (float*)d_out;

  zero_out_k<<<1, 64, 0, stream>>>(out);   // d_out is poisoned 0xAA before every replay
  cde_main<<<BB/MROWS, NTHR, 0, stream>>>(coeffs, y, times, W_init, b_init,
                                          W_in, b_in, W_h, b_h, W_out, b_out,
                                          W_read, b_read, out);
}